// Round 22
// baseline (266.017 us; speedup 1.0000x reference)
//
#include <hip/hip_runtime.h>
#include <stdint.h>

typedef __attribute__((ext_vector_type(4))) int i32x4;

#define TN 2.50f          // normalized filter threshold (units of s_p)
#define PMARG 0.10f       // pool margin: must absorb enc_b bias (max ~0.045) + quant noise
#define CAP 224
#define SORT2 128

__device__ inline float bf2f(unsigned short u) { return __uint_as_float(((unsigned int)u) << 16); }
__device__ inline unsigned short f2bf(float f) {
    unsigned int x = __float_as_uint(f);
    return (unsigned short)((x + 0x7FFFu + ((x >> 16) & 1u)) >> 16);  // RNE
}

template <typename T>
__device__ inline void gload16(const T* g, T* l) {
    __builtin_amdgcn_global_load_lds((const __attribute__((address_space(1))) void*)g,
                                     (__attribute__((address_space(3))) void*)l, 16, 0, 0);
}

// ---- T1Q: fused transpose + x-quant, register-resident.
//      Block = (b, hwg): 16 pixels. Thread: channels c=tid, tid+256 x 16 hw (64B chunks).
//      Emits xTf (exact f32), xq (bit-identical int8: max is order-free), thr, sx, S/Q. ----
__global__ __launch_bounds__(256) void t1q(const float* __restrict__ x, float* __restrict__ xTf,
                                           signed char* __restrict__ xq, float* __restrict__ sx,
                                           float* __restrict__ thr, double* __restrict__ S,
                                           double* __restrict__ Q) {
    __shared__ float redm[4][16], reds[4][16], binv[16];
    int b = blockIdx.x >> 4, hw0 = (blockIdx.x & 15) * 16;
    int tid = threadIdx.x, lane = tid & 63, wv = tid >> 6;
    float v[2][16];
    float pm[16], ps[16];
#pragma unroll
    for (int q = 0; q < 16; q++) { pm[q] = 0.0f; ps[q] = 0.0f; }
#pragma unroll
    for (int h = 0; h < 2; h++) {
        int c = h * 256 + tid;
        const float4* src = (const float4*)(x + ((size_t)(b * 512 + c)) * 256 + hw0);
        float4 a0 = src[0], a1 = src[1], a2 = src[2], a3 = src[3];
        v[h][0] = a0.x; v[h][1] = a0.y; v[h][2] = a0.z; v[h][3] = a0.w;
        v[h][4] = a1.x; v[h][5] = a1.y; v[h][6] = a1.z; v[h][7] = a1.w;
        v[h][8] = a2.x; v[h][9] = a2.y; v[h][10] = a2.z; v[h][11] = a2.w;
        v[h][12] = a3.x; v[h][13] = a3.y; v[h][14] = a3.z; v[h][15] = a3.w;
        float s1 = 0.0f, s2 = 0.0f;
#pragma unroll
        for (int q = 0; q < 16; q++) {
            float t = v[h][q];
            s1 += t;
            s2 += t * t;
            pm[q] = fmaxf(pm[q], fabsf(t));
            ps[q] += t * t;
        }
        atomicAdd(&S[c], (double)s1);
        atomicAdd(&Q[c], (double)s2);
    }
    // wave-level reduce of per-pixel max / ss
#pragma unroll
    for (int off = 32; off; off >>= 1)
#pragma unroll
        for (int q = 0; q < 16; q++) {
            pm[q] = fmaxf(pm[q], __shfl_xor(pm[q], off, 64));
            ps[q] += __shfl_xor(ps[q], off, 64);
        }
    if (lane == 0)
#pragma unroll
        for (int q = 0; q < 16; q++) { redm[wv][q] = pm[q]; reds[wv][q] = ps[q]; }
    __syncthreads();
    if (tid < 16) {
        int q = tid;
        float m = fmaxf(fmaxf(redm[0][q], redm[1][q]), fmaxf(redm[2][q], redm[3][q]));
        float ss = reds[0][q] + reds[1][q] + reds[2][q] + reds[3][q];
        m = fmaxf(m, 1e-20f);
        int p = b * 256 + hw0 + q;
        sx[p] = m * (1.0f / 127.0f);
        thr[p] = TN * sqrtf(ss * (1.0f / 512.0f));
        binv[q] = 127.0f / m;
    }
    __syncthreads();
    float bi[16];
#pragma unroll
    for (int q = 0; q < 16; q++) bi[q] = binv[q];
#pragma unroll
    for (int h = 0; h < 2; h++) {
        int c = h * 256 + tid;
#pragma unroll
        for (int q = 0; q < 16; q++) {
            size_t o = (size_t)(b * 256 + hw0 + q) * 512 + c;
            float val = v[h][q];
            xTf[o] = val;
            xq[o] = (signed char)__float2int_rn(val * bi[q]);
        }
    }
}

// ---- quantize enc_w [16384][512] rows to int8, per-row max scale ----
__global__ __launch_bounds__(256) void k_quantw(const float* __restrict__ w, signed char* __restrict__ wq,
                                                float* __restrict__ sw) {
    int row = blockIdx.x * 4 + (threadIdx.x >> 6), lane = threadIdx.x & 63;
    const float4* s4 = (const float4*)(w + (size_t)row * 512);
    float4 a = s4[lane * 2], b = s4[lane * 2 + 1];
    float m = fmaxf(fmaxf(fmaxf(fabsf(a.x), fabsf(a.y)), fmaxf(fabsf(a.z), fabsf(a.w))),
                    fmaxf(fmaxf(fabsf(b.x), fabsf(b.y)), fmaxf(fabsf(b.z), fabsf(b.w))));
    for (int off = 32; off; off >>= 1) m = fmaxf(m, __shfl_xor(m, off, 64));
    m = fmaxf(m, 1e-20f);
    float inv = 127.0f / m;
    int q0 = __float2int_rn(a.x * inv), q1 = __float2int_rn(a.y * inv);
    int q2 = __float2int_rn(a.z * inv), q3 = __float2int_rn(a.w * inv);
    int q4 = __float2int_rn(b.x * inv), q5 = __float2int_rn(b.y * inv);
    int q6 = __float2int_rn(b.z * inv), q7 = __float2int_rn(b.w * inv);
    unsigned int w0 = (q0 & 255) | ((q1 & 255) << 8) | ((q2 & 255) << 16) | ((unsigned)(q3 & 255) << 24);
    unsigned int w1 = (q4 & 255) | ((q5 & 255) << 8) | ((q6 & 255) << 16) | ((unsigned)(q7 & 255) << 24);
    *(uint2*)(wq + (size_t)row * 512 + lane * 8) = make_uint2(w0, w1);
    if (lane == 0) sw[row] = m * (1.0f / 127.0f);
}

// ---------------- T3: dec_w [512][16384] -> dec_wT [16384][512] bf16 ----------------
__global__ __launch_bounds__(256) void t3_decw(const float* __restrict__ w, unsigned short* __restrict__ wT) {
    __shared__ float tile[64][65];
    int l0 = blockIdx.x * 64, d0 = blockIdx.y * 64;
    int tid = threadIdx.x, g = tid >> 6, ln = tid & 63;
    for (int i = 0; i < 16; i++) {
        int dl = g * 16 + i;
        tile[dl][ln] = w[(size_t)(d0 + dl) * 16384 + l0 + ln];
    }
    __syncthreads();
    for (int i = 0; i < 16; i++) {
        int ll = g * 16 + i;
        wT[(size_t)(l0 + ll) * 512 + d0 + ln] = f2bf(tile[ln][ll]);
    }
}

// ---- GEMM int8 (frozen): 128x128, BK=64, 256 thr, 3-buf 48KB (3 blocks/CU),
//      depth-2 counted vmcnt(4), XOR swizzle, XCD swizzle ----
#define SBAR                                   \
    __builtin_amdgcn_sched_barrier(0);         \
    __builtin_amdgcn_s_barrier();              \
    __builtin_amdgcn_sched_barrier(0);
#define VMW4 { asm volatile("s_waitcnt vmcnt(4)" ::: "memory"); __builtin_amdgcn_sched_barrier(0); }
#define VMW0 { asm volatile("s_waitcnt vmcnt(0)" ::: "memory"); __builtin_amdgcn_sched_barrier(0); }

__global__ __launch_bounds__(256) void k_gemm(const signed char* __restrict__ xq,
                                              const signed char* __restrict__ wq,
                                              const float* __restrict__ sx, const float* __restrict__ sw,
                                              const float* __restrict__ thr,
                                              int* __restrict__ cnt, unsigned int* __restrict__ cand) {
    __shared__ __align__(16) signed char As[3][128 * 64];  // 3 x 8KB
    __shared__ __align__(16) signed char Bs[3][128 * 64];  // 3 x 8KB  (tot 48KB)
    int tid = threadIdx.x, wid = tid >> 6, lane = tid & 63;

    int lin = blockIdx.x + blockIdx.y * gridDim.x;   // grid (128 n, 32 m)
    int swz = (lin & 7) * 512 + (lin >> 3);
    int bx = swz >> 5;          // n-block 0..127
    int by = swz & 31;          // m-block 0..31
    int m0 = by * 128, n0 = bx * 128;
    int wr = wid >> 1, wc = wid & 1;   // 2x2 waves; per-wave 64x64

    i32x4 acc[4][4];
#pragma unroll
    for (int mi = 0; mi < 4; mi++)
#pragma unroll
        for (int ni = 0; ni < 4; ni++)
#pragma unroll
            for (int j = 0; j < 4; j++) acc[mi][ni][j] = 0;

    int srow = lane >> 2;                 // 0..15 within chunk

#define STAGE(bufi, kt)                                                                            \
    {                                                                                              \
        signed char* Ad = &As[bufi][0];                                                            \
        signed char* Bd = &Bs[bufi][0];                                                            \
        _Pragma("unroll")                                                                          \
        for (int i_ = 0; i_ < 2; i_++) {                                                           \
            int ch_ = wid * 2 + i_;                                                                \
            int row_ = ch_ * 16 + srow;                                                            \
            int sc_ = (((lane & 3) ^ ((row_ >> 1) & 3)) << 4);                                     \
            gload16(xq + (size_t)(m0 + row_) * 512 + (kt) + sc_, Ad + ch_ * 1024);                 \
            gload16(wq + (size_t)(n0 + row_) * 512 + (kt) + sc_, Bd + ch_ * 1024);                 \
        }                                                                                          \
    }

    STAGE(0, 0)
    STAGE(1, 64)     // depth-2: 8 loads/wave in flight
#pragma unroll
    for (int t = 0; t < 8; t++) {
        int cur = t % 3;
        if (t < 7) VMW4      // tile t's 4 loads done; tile t+1's 4 stay in flight
        else VMW0
        SBAR                  // tile t visible; readers of buf (t+2)%3 retired
        if (t < 6) STAGE((t + 2) % 3, (t + 2) * 64)
        const signed char* Ac = &As[cur][0];
        const signed char* Bc = &Bs[cur][0];
        i32x4 a[4], b[4];
#pragma unroll
        for (int mi = 0; mi < 4; mi++) {
            int r = wr * 64 + mi * 16 + (lane & 15);
            int slot = (lane >> 4) ^ ((r >> 1) & 3);
            a[mi] = *(const i32x4*)&Ac[r * 64 + slot * 16];
        }
#pragma unroll
        for (int ni = 0; ni < 4; ni++) {
            int r = wc * 64 + ni * 16 + (lane & 15);
            int slot = (lane >> 4) ^ ((r >> 1) & 3);
            b[ni] = *(const i32x4*)&Bc[r * 64 + slot * 16];
        }
#pragma unroll
        for (int mi = 0; mi < 4; mi++)
#pragma unroll
            for (int ni = 0; ni < 4; ni++)
                acc[mi][ni] = __builtin_amdgcn_mfma_i32_16x16x64_i8(a[mi], b[ni], acc[mi][ni], 0, 0, 0);
    }
#undef STAGE

    float swl[4];
#pragma unroll
    for (int ni = 0; ni < 4; ni++) swl[ni] = sw[n0 + wc * 64 + ni * 16 + (lane & 15)];
#pragma unroll
    for (int mi = 0; mi < 4; mi++)
#pragma unroll
        for (int j = 0; j < 4; j++) {
            int pixel = m0 + wr * 64 + mi * 16 + (lane >> 4) * 4 + j;
            float tv = thr[pixel];
            float sxp = sx[pixel];
#pragma unroll
            for (int ni = 0; ni < 4; ni++) {
                float v = (float)acc[mi][ni][j] * (sxp * swl[ni]);
                if (v >= tv) {
                    int lat = n0 + wc * 64 + ni * 16 + (lane & 15);
                    int slot = atomicAdd(&cnt[pixel], 1);
                    if (slot < CAP) cand[pixel * CAP + slot] = ((unsigned)f2bf(v) << 16) | (unsigned)lat;
                }
            }
        }
}

// ---- top-32 + decode fused: 8-iter binary search, exact seqFMA rescore of pool,
//      O(pool^2) rank-selection, then sparse decode + l2 using xrow in LDS ----
__global__ __launch_bounds__(256) void k_topk(const float* __restrict__ xTf, const float* __restrict__ enc_w,
                                              const float* __restrict__ enc_b, const int* __restrict__ cnt,
                                              const unsigned int* __restrict__ cand,
                                              const unsigned short* __restrict__ dwT,
                                              const float* __restrict__ dec_b,
                                              float* __restrict__ out_acts, float* __restrict__ out_idx,
                                              float* __restrict__ out_sae, double* __restrict__ l2acc) {
    __shared__ __align__(16) float xrow[512];
    __shared__ unsigned long long skey2[SORT2];
    __shared__ int npool;
    __shared__ float sa[32];
    __shared__ int si[32];
    __shared__ double red[256];
    int p = blockIdx.x, tid = threadIdx.x;
    if (tid < 128) ((float4*)xrow)[tid] = ((const float4*)(xTf + (size_t)p * 512))[tid];
    if (tid == 0) npool = 0;
    int c = cnt[p];
    if (c > CAP) c = CAP;
    unsigned int pk = (tid < c) ? cand[p * CAP + tid] : 0u;
    unsigned int bfb = pk >> 16;
    int lo = 0x4000, hi = 0x40FF;
    for (int it = 0; it < 8; it++) {
        int mid = (lo + hi + 1) >> 1;
        int n = __syncthreads_count(tid < c && bfb >= (unsigned)mid);
        if (n >= 32) lo = mid; else hi = mid - 1;
    }
    float pthr = bf2f((unsigned short)lo) - PMARG;
    unsigned long long mykey = ~0ull;
    float act = 0.0f;
    int lat = 0;
    bool inpool = false;
    if (tid < c && bf2f((unsigned short)bfb) >= pthr) {
        int slot = atomicAdd(&npool, 1);
        if (slot < SORT2) {
            inpool = true;
            lat = (int)(pk & 16383u);
            const float4* w4 = (const float4*)(enc_w + (size_t)lat * 512);
            const float4* x4 = (const float4*)xrow;
            float acc = 0.0f;
            for (int q = 0; q < 128; q++) {
                float4 w = w4[q];
                float4 xv = x4[q];
                acc = __fmaf_rn(xv.x, w.x, acc);
                acc = __fmaf_rn(xv.y, w.y, acc);
                acc = __fmaf_rn(xv.z, w.z, acc);
                acc = __fmaf_rn(xv.w, w.w, acc);
            }
            float pre = __fadd_rn(acc, enc_b[lat]);
            if (pre > 0.0f) {
                mykey = ((unsigned long long)(0xFFFFFFFFu - __float_as_uint(pre)) << 32) | (unsigned)lat;
                act = pre;
            } else {
                mykey = 0xFFFFFFFF00000000ull | (unsigned)lat;
                act = 0.0f;
            }
            skey2[slot] = mykey;
        }
    }
    __syncthreads();
    int b = p >> 8, hw = p & 255;
    if (inpool) {
        int np2 = npool < SORT2 ? npool : SORT2;
        int rank = 0;
        for (int j = 0; j < np2; j++) rank += (skey2[j] < mykey) ? 1 : 0;
        if (rank < 32) {
            sa[rank] = act;
            si[rank] = lat;
            out_acts[(size_t)b * 8192 + rank * 256 + hw] = act;
            out_idx[(size_t)b * 8192 + rank * 256 + hw] = (float)lat;
        }
    }
    __syncthreads();
    float a0 = dec_b[tid], a1 = dec_b[tid + 256];
    for (int j = 0; j < 32; j++) {
        float a = sa[j];
        const unsigned short* r = dwT + (size_t)si[j] * 512;
        a0 += a * bf2f(r[tid]);
        a1 += a * bf2f(r[tid + 256]);
    }
    size_t o0 = (size_t)b * 131072 + (size_t)tid * 256 + hw;
    size_t o1 = o0 + 65536;
    out_sae[o0] = a0;
    out_sae[o1] = a1;
    float e0 = a0 - xrow[tid], e1 = a1 - xrow[tid + 256];
    red[tid] = (double)e0 * e0 + (double)e1 * e1;
    __syncthreads();
    for (int s = 128; s; s >>= 1) {
        if (tid < s) red[tid] += red[tid + s];
        __syncthreads();
    }
    if (tid == 0) atomicAdd(l2acc, red[0]);
}

// ---------------- finalize fvu ----------------
__global__ __launch_bounds__(256) void k_fin(const double* __restrict__ l2, const double* __restrict__ S,
                                             const double* __restrict__ Q, float* __restrict__ out_sc) {
    __shared__ double red[256];
    int tid = threadIdx.x;
    double tv = 0;
    for (int c = tid; c < 512; c += 256) tv += Q[c] - S[c] * S[c] * (1.0 / 4096.0);
    red[tid] = tv;
    __syncthreads();
    for (int s = 128; s; s >>= 1) {
        if (tid < s) red[tid] += red[tid + s];
        __syncthreads();
    }
    if (tid == 0) {
        double fvu = l2[0] / red[0];
        out_sc[0] = (float)fvu;
        out_sc[1] = 0.0f;
        out_sc[2] = 0.0f;
    }
}

extern "C" void kernel_launch(void* const* d_in, const int* in_sizes, int n_in,
                              void* d_out, int out_size, void* d_ws, size_t ws_size,
                              hipStream_t stream) {
    const float* x = (const float*)d_in[0];
    const float* enc_w = (const float*)d_in[1];
    const float* enc_b = (const float*)d_in[2];
    const float* dec_w = (const float*)d_in[3];
    const float* dec_b = (const float*)d_in[4];
    (void)in_sizes; (void)n_in; (void)out_size; (void)ws_size;

    char* ws = (char*)d_ws;
    float* xTf = (float*)ws;                                   //  8 MB
    signed char* xq = (signed char*)(ws + 8388608);            //  2 MB
    signed char* wq = (signed char*)(ws + 10485760);           //  8 MB
    unsigned short* dwT = (unsigned short*)(ws + 18874368);    // 16 MB
    unsigned int* cand = (unsigned int*)(ws + 35651584);       //  3.5 MB (4096*224*4)
    // contiguous zero-init region: cnt | S | Q | l2
    int* cnt = (int*)(ws + 39321600);                          // 16 KB
    double* S = (double*)(ws + 39337984);                      //  4 KB
    double* Q = (double*)(ws + 39342080);                      //  4 KB
    double* l2 = (double*)(ws + 39346176);                     //  8 B
    float* thr = (float*)(ws + 39350272);                      // 16 KB (written directly)
    float* sx = (float*)(ws + 39366656);                       // 16 KB
    float* sw = (float*)(ws + 39383040);                       // 64 KB

    float* out = (float*)d_out;   // reference outputs are float32
    float* out_sae = out;
    float* out_acts = out + 2097152;
    float* out_idx = out + 2228224;
    float* out_sc = out + 2359296;

    hipMemsetAsync(cnt, 0, 16384 + 4096 + 4096 + 8, stream);

    t1q<<<256, 256, 0, stream>>>(x, xTf, xq, sx, thr, S, Q);
    k_quantw<<<4096, 256, 0, stream>>>(enc_w, wq, sw);
    t3_decw<<<dim3(256, 8), 256, 0, stream>>>(dec_w, dwT);
    k_gemm<<<dim3(128, 32), 256, 0, stream>>>(xq, wq, sx, sw, thr, cnt, cand);
    k_topk<<<4096, 256, 0, stream>>>(xTf, enc_w, enc_b, cnt, cand, dwT, dec_b,
                                     out_acts, out_idx, out_sae, l2);
    k_fin<<<1, 256, 0, stream>>>(l2, S, Q, out_sc);
}